// Round 22
// baseline (289.573 us; speedup 1.0000x reference)
//
#include <hip/hip_runtime.h>

#define N_SRC   100000
#define N_TGT   50000
#define N_EDGES 1000000
#define NEG     0.2
#define NXCD    8
#define TPART   (N_TGT / NXCD)   // 6250
#define SPART   (N_SRC / NXCD)   // 12500

#define GBLK_S  1563             // ceil(N_SRC/64)
#define GBLK_T  782              // ceil(N_TGT/64)
#define GBLK    (GBLK_S + GBLK_T)
#define NHQ     2048             // hist blocks (256 per XCD), dispatched FIRST
#define NSC     2048             // scatter blocks
#define QCAP    131072           // queue entries per XCD per side (mean 125000, sigma~330)

// ===========================================================================
// R22: XCD-local hist via per-XCD payload queues (in d_out scratch).
//  - hist: each XCD scans all edges, claims its node partitions; cnt atomics
//    are L2-LOCAL (no cross-XCD counter-line ping-pong = R21's 94us hist).
//    Queue entry (16B) = {node|rank, other, nbhd, 0} appended densely via
//    block-reserved base (1 global tail atomic/block/side) + LDS offsets.
//  - scatter: pure streaming — sequential queue read (L2-hot, same XCD),
//    8B XCD-local store. No filtering, no 8x re-scan.
//  - gemm rides behind hist blocks (R21: hosts absorb gemm at ~50% cost).
//  - scan/gather/gemm bodies unchanged from R20 (best=278.8).
// d_out-as-scratch is legal: queues are fully consumed by scatter before
// gather overwrites every output element.
// ===========================================================================

// ---------------------------------------------------------------------------
#define XS2 65
__global__ __launch_bounds__(256) void fused_histq_gemm(
    const int* __restrict__ rows, const int* __restrict__ cols,
    const float* __restrict__ nbhd,
    int* __restrict__ cnt_r, int* __restrict__ cnt_c,
    int* __restrict__ qtails, uint4* __restrict__ qT, uint4* __restrict__ qS,
    const float* __restrict__ x_source, const float* __restrict__ x_target,
    const float* __restrict__ w_s, const float* __restrict__ w_t,
    const float* __restrict__ att,
    float* __restrict__ s_msg, float* __restrict__ t_msg,
    double* __restrict__ es_d, double* __restrict__ et_d)
{
    __shared__ float xs[64 * XS2];         // gemm branch
    __shared__ double eds[4][64];          // gemm branch
    __shared__ int hsum[8];                // hist: per-wave counts (4 waves x 2)
    __shared__ int sbase[2];               // hist: block's reserved queue bases
    __shared__ int stail[2];               // hist: block-local running offsets
    const int tid = threadIdx.x;

    if (blockIdx.x < NHQ) {
        // ---------------- hist branch (XCD-partitioned) ----------------
        const int k    = blockIdx.x & 7;
        const int ibx  = blockIdx.x >> 3;
        const int lane = tid & 63, wid = tid >> 6;
        const unsigned lo_r = k * TPART, lo_c = k * SPART;
        const int step = (NHQ >> 3) * 256;           // 65536

        // pass A: count this block's partition hits
        int nT = 0, nS = 0;
        for (int ib = ibx * 256; ib < N_EDGES; ib += step) {
            const int i = ib + tid;
            unsigned r = 0xFFFFFFFFu, c = 0xFFFFFFFFu;
            if (i < N_EDGES) { r = rows[i]; c = cols[i]; }
            nT += ((r - lo_r) < TPART);
            nS += ((c - lo_c) < SPART);
        }
        #pragma unroll
        for (int d = 32; d; d >>= 1) { nT += __shfl_xor(nT, d); nS += __shfl_xor(nS, d); }
        if (lane == 0) { hsum[wid] = nT; hsum[4 + wid] = nS; }
        __syncthreads();
        if (tid == 0) {
            const int tT = hsum[0] + hsum[1] + hsum[2] + hsum[3];
            const int tS = hsum[4] + hsum[5] + hsum[6] + hsum[7];
            sbase[0] = atomicAdd(&qtails[k * 16],       tT);
            sbase[1] = atomicAdd(&qtails[(8 + k) * 16], tS);
            stail[0] = 0; stail[1] = 0;
        }
        __syncthreads();
        const int bT = sbase[0], bS = sbase[1];
        uint4* qTk = qT + (size_t)k * QCAP;
        uint4* qSk = qS + (size_t)k * QCAP;

        // pass B: L2-local cnt atomics + dense queue append
        for (int ib = ibx * 256; ib < N_EDGES; ib += step) {
            const int i = ib + tid;
            unsigned r = 0xFFFFFFFFu, c = 0xFFFFFFFFu;
            if (i < N_EDGES) { r = rows[i]; c = cols[i]; }
            const bool mr = (r - lo_r) < TPART;
            const bool mc = (c - lo_c) < SPART;
            unsigned nbu = 0;
            if (mr | mc) nbu = (unsigned)__float_as_int(nbhd[i]);

            const unsigned long long mT = __ballot(mr);
            if (mT) {
                const int ldr = __ffsll((unsigned long long)mT) - 1;
                int wb;
                if (lane == ldr) wb = atomicAdd(&stail[0], (int)__popcll(mT));
                wb = __shfl(wb, ldr);
                if (mr) {
                    const unsigned kr = (unsigned)atomicAdd(&cnt_r[r], 1);
                    const int pos = bT + wb + (int)__popcll(mT & ((1ull << lane) - 1));
                    qTk[pos] = make_uint4(r | (kr << 16), c, nbu, 0u);
                }
            }
            const unsigned long long mS = __ballot(mc);
            if (mS) {
                const int ldr = __ffsll((unsigned long long)mS) - 1;
                int wb;
                if (lane == ldr) wb = atomicAdd(&stail[1], (int)__popcll(mS));
                wb = __shfl(wb, ldr);
                if (mc) {
                    const unsigned kc = (unsigned)atomicAdd(&cnt_c[c], 1);
                    const int pos = bS + wb + (int)__popcll(mS & ((1ull << lane) - 1));
                    qSk[pos] = make_uint4(c | (kc << 17), r, nbu, 0u);
                }
            }
        }
        return;
    }

    // ---------------- gemm branch (R20 body, unchanged numerics) ----------------
    const int gi = blockIdx.x - NHQ;

    const float* x; const float* w; int att_off, nrows, bblk;
    float* msg; double* evec;
    if (gi < GBLK_S) { x = x_source; w = w_s; att_off = 0;  nrows = N_SRC;
                       msg = s_msg;  evec = es_d; bblk = gi; }
    else             { x = x_target; w = w_t; att_off = 64; nrows = N_TGT;
                       msg = t_msg;  evec = et_d; bblk = gi - GBLK_S; }

    const int lane = tid & 63;
    const int part = tid >> 6;
    const int c0   = __builtin_amdgcn_readfirstlane(part << 4);
    const int row0 = bblk * 64;
    const int row  = row0 + lane;
    const bool act = row < nrows;

    float acc[16];
    #pragma unroll
    for (int c = 0; c < 16; ++c) acc[c] = 0.f;

    const int xbase = lane * XS2;

    #pragma unroll
    for (int it = 0; it < 4; ++it) {
        const int fid = tid + it * 256;
        const int r = fid >> 4, q = fid & 15;
        if (row0 + r < nrows) {
            const float4 v = *(const float4*)(x + (size_t)(row0 + r) * 128 + 4 * q);
            float* d = &xs[r * XS2 + 4 * q];
            d[0] = v.x; d[1] = v.y; d[2] = v.z; d[3] = v.w;
        }
    }
    __syncthreads();

    float4 pre[4];
    #pragma unroll
    for (int it = 0; it < 4; ++it) {
        const int fid = tid + it * 256;
        const int r = fid >> 4, q = fid & 15;
        pre[it] = (row0 + r < nrows)
            ? *(const float4*)(x + (size_t)(row0 + r) * 128 + 64 + 4 * q)
            : make_float4(0.f, 0.f, 0.f, 0.f);
    }

    for (int kc = 0; kc < 64; kc += 16) {
        #pragma unroll
        for (int kk = 0; kk < 16; ++kk) {
            const float xk = xs[xbase + kc + kk];
            const float* wr = w + (size_t)(kc + kk) * 64 + c0;
            #pragma unroll
            for (int c = 0; c < 16; ++c)
                acc[c] = fmaf(xk, wr[c], acc[c]);
        }
    }
    __syncthreads();

    #pragma unroll
    for (int it = 0; it < 4; ++it) {
        const int fid = tid + it * 256;
        const int r = fid >> 4, q = fid & 15;
        float* d = &xs[r * XS2 + 4 * q];
        d[0] = pre[it].x; d[1] = pre[it].y; d[2] = pre[it].z; d[3] = pre[it].w;
    }
    __syncthreads();

    for (int kc = 0; kc < 64; kc += 16) {
        #pragma unroll
        for (int kk = 0; kk < 16; ++kk) {
            const float xk = xs[xbase + kc + kk];
            const float* wr = w + (size_t)(64 + kc + kk) * 64 + c0;
            #pragma unroll
            for (int c = 0; c < 16; ++c)
                acc[c] = fmaf(xk, wr[c], acc[c]);
        }
    }

    double e = 0.0;
    #pragma unroll
    for (int c = 0; c < 16; ++c)
        e += (double)acc[c] * (double)att[att_off + c0 + c];
    eds[part][lane] = e;
    __syncthreads();
    if (part == 0 && act)
        evec[row] = eds[0][lane] + eds[1][lane] + eds[2][lane] + eds[3][lane];

    if (act) {
        float* mo = msg + (size_t)row * 64 + c0;
        #pragma unroll
        for (int q = 0; q < 4; ++q)
            *(float4*)(mo + 4 * q) = *(float4*)(acc + 4 * q);
    }
}

// ---------------------------------------------------------------------------
// Exclusive scan, tiled + coalesced. block 0 -> rows (N_TGT), 1 -> cols (N_SRC).
// ---------------------------------------------------------------------------
__global__ __launch_bounds__(1024) void scan_two(
    const int* __restrict__ cnt_r, const int* __restrict__ cnt_c,
    int* __restrict__ ptr_r, int* __restrict__ ptr_c)
{
    const int n    = blockIdx.x ? N_SRC : N_TGT;
    const int* cnt = blockIdx.x ? cnt_c : cnt_r;
    int* ptr       = blockIdx.x ? ptr_c : ptr_r;
    const int tid  = threadIdx.x;
    const int lane = tid & 63, wid = tid >> 6;

    __shared__ int wsum[16];
    __shared__ int s_carry;
    if (tid == 0) s_carry = 0;
    __syncthreads();

    for (int base = 0; base < n; base += 4096) {
        const int idx = base + tid * 4;
        int4 v = make_int4(0, 0, 0, 0);
        if (idx + 3 < n) {
            v = *(const int4*)(cnt + idx);
        } else if (idx < n) {
            v.x = cnt[idx];
            if (idx + 1 < n) v.y = cnt[idx + 1];
            if (idx + 2 < n) v.z = cnt[idx + 2];
        }
        const int s = v.x + v.y + v.z + v.w;

        int p = s;
        #pragma unroll
        for (int d = 1; d < 64; d <<= 1) {
            int t = __shfl_up(p, d);
            if (lane >= d) p += t;
        }
        if (lane == 63) wsum[wid] = p;
        __syncthreads();
        if (tid == 0) {
            int a = 0;
            #pragma unroll
            for (int i = 0; i < 16; ++i) { int t = wsum[i]; wsum[i] = a; a += t; }
        }
        __syncthreads();

        int run = s_carry + wsum[wid] + (p - s);
        if (idx     < n) ptr[idx]     = run; run += v.x;
        if (idx + 1 < n) ptr[idx + 1] = run; run += v.y;
        if (idx + 2 < n) ptr[idx + 2] = run; run += v.z;
        if (idx + 3 < n) ptr[idx + 3] = run; run += v.w;

        __syncthreads();
        if (tid == 1023) s_carry = run;
        __syncthreads();
    }
    if (tid == 0) ptr[n] = s_carry;
}

// ---------------------------------------------------------------------------
// Scatter: pure streaming per-XCD queue drain. Sequential 16B reads (L2-hot,
// same XCD that wrote them) -> 8B XCD-local stores. No filter, no re-scan.
// ---------------------------------------------------------------------------
__global__ __launch_bounds__(256) void scatter_queue(
    const uint4* __restrict__ qT, const uint4* __restrict__ qS,
    const int* __restrict__ qtails,
    const int* __restrict__ ptr_r, const int* __restrict__ ptr_c,
    unsigned long long* __restrict__ srtT, unsigned long long* __restrict__ srtS)
{
    const int k   = blockIdx.x & 7;
    const int ibx = blockIdx.x >> 3;
    const int step = (NSC >> 3) * 256;
    const int nT = qtails[k * 16];
    const int nS = qtails[(8 + k) * 16];
    const uint4* qTk = qT + (size_t)k * QCAP;
    const uint4* qSk = qS + (size_t)k * QCAP;

    for (int j = ibx * 256 + threadIdx.x; j < nT; j += step) {
        const uint4 e = qTk[j];
        const unsigned r = e.x & 0xFFFFu, kr = e.x >> 16;
        srtT[ptr_r[r] + kr] = ((unsigned long long)e.z << 32) | e.y;
    }
    for (int j = ibx * 256 + threadIdx.x; j < nS; j += step) {
        const uint4 e = qSk[j];
        const unsigned c = e.x & 0x1FFFFu, kc = e.x >> 17;
        srtS[ptr_c[c] + kc] = ((unsigned long long)e.z << 32) | e.y;
    }
}

// ---------------------------------------------------------------------------
// Gather (R20 body): one wave per output row, lane = feature. den f64;
// numerator f32; 8-deep load ILP.
// ---------------------------------------------------------------------------
__global__ __launch_bounds__(256) void gather_both(
    const int2* __restrict__ srtT, const int* __restrict__ ptr_r,
    const float* __restrict__ s_msg, float* __restrict__ msg_tgt,
    const int2* __restrict__ srtS, const int* __restrict__ ptr_c,
    const float* __restrict__ t_msg, float* __restrict__ msg_src,
    const double* __restrict__ es_d, const double* __restrict__ et_d)
{
    const int gw   = (blockIdx.x * blockDim.x + threadIdx.x) >> 6;
    const int lane = threadIdx.x & 63;

    const int2* srt; const int* ptr; const float* min_; float* out;
    const double* other_d; double base; int row;
    if (gw < N_TGT) {
        srt = srtT; ptr = ptr_r; min_ = s_msg; out = msg_tgt;
        other_d = es_d; row = gw; base = et_d[row];
    } else {
        row = gw - N_TGT;
        if (row >= N_SRC) return;
        srt = srtS; ptr = ptr_c; min_ = t_msg; out = msg_src;
        other_d = et_d; base = es_d[row];
    }

    const int b = ptr[row], e = ptr[row + 1];
    double den = 0.0;
    float a0 = 0.f, a1 = 0.f, a2 = 0.f, a3 = 0.f;

    for (int j0 = b; j0 < e; j0 += 64) {
        const int m = e - j0;
        int oidx = 0; double v = 0.0; float wf = 0.f;
        if (lane < m) {
            const int2 pay = srt[j0 + lane];
            oidx = pay.x;
            const float nb = __int_as_float(pay.y);
            const double sv = base + other_d[oidx];
            v = (sv >= 0.0) ? sv : NEG * sv;
            wf = (float)(v * (double)nb);
        }
        den += v;

        const int cnt = m < 64 ? m : 64;
        int j = 0;
        for (; j + 7 < cnt; j += 8) {
            const int   c0_ = __shfl(oidx, j);     const float w0 = __shfl(wf, j);
            const int   c1_ = __shfl(oidx, j + 1); const float w1 = __shfl(wf, j + 1);
            const int   c2_ = __shfl(oidx, j + 2); const float w2 = __shfl(wf, j + 2);
            const int   c3_ = __shfl(oidx, j + 3); const float w3 = __shfl(wf, j + 3);
            const int   c4_ = __shfl(oidx, j + 4); const float w4 = __shfl(wf, j + 4);
            const int   c5_ = __shfl(oidx, j + 5); const float w5 = __shfl(wf, j + 5);
            const int   c6_ = __shfl(oidx, j + 6); const float w6 = __shfl(wf, j + 6);
            const int   c7_ = __shfl(oidx, j + 7); const float w7 = __shfl(wf, j + 7);
            const float m0 = min_[(size_t)c0_ * 64 + lane];
            const float m1 = min_[(size_t)c1_ * 64 + lane];
            const float m2 = min_[(size_t)c2_ * 64 + lane];
            const float m3 = min_[(size_t)c3_ * 64 + lane];
            const float m4 = min_[(size_t)c4_ * 64 + lane];
            const float m5 = min_[(size_t)c5_ * 64 + lane];
            const float m6 = min_[(size_t)c6_ * 64 + lane];
            const float m7 = min_[(size_t)c7_ * 64 + lane];
            a0 = fmaf(w0, m0, a0); a1 = fmaf(w1, m1, a1);
            a2 = fmaf(w2, m2, a2); a3 = fmaf(w3, m3, a3);
            a0 = fmaf(w4, m4, a0); a1 = fmaf(w5, m5, a1);
            a2 = fmaf(w6, m6, a2); a3 = fmaf(w7, m7, a3);
        }
        for (; j + 3 < cnt; j += 4) {
            const int   c0_ = __shfl(oidx, j);     const float w0 = __shfl(wf, j);
            const int   c1_ = __shfl(oidx, j + 1); const float w1 = __shfl(wf, j + 1);
            const int   c2_ = __shfl(oidx, j + 2); const float w2 = __shfl(wf, j + 2);
            const int   c3_ = __shfl(oidx, j + 3); const float w3 = __shfl(wf, j + 3);
            a0 = fmaf(w0, min_[(size_t)c0_ * 64 + lane], a0);
            a1 = fmaf(w1, min_[(size_t)c1_ * 64 + lane], a1);
            a2 = fmaf(w2, min_[(size_t)c2_ * 64 + lane], a2);
            a3 = fmaf(w3, min_[(size_t)c3_ * 64 + lane], a3);
        }
        for (; j < cnt; ++j) {
            const int   c = __shfl(oidx, j);
            const float w = __shfl(wf, j);
            a0 = fmaf(w, min_[(size_t)c * 64 + lane], a0);
        }
    }
    #pragma unroll
    for (int s = 32; s; s >>= 1) den += __shfl_xor(den, s);
    const double inv = (den != 0.0) ? 1.0 / den : 0.0;
    const double acc = (double)((a0 + a1) + (a2 + a3));
    out[(size_t)row * 64 + lane] = (float)(acc * inv);
}

// ===========================================================================
extern "C" void kernel_launch(void* const* d_in, const int* in_sizes, int n_in,
                              void* d_out, int out_size, void* d_ws, size_t ws_size,
                              hipStream_t stream)
{
    const float* x_source = (const float*)d_in[0];
    const float* x_target = (const float*)d_in[1];
    const float* w_s      = (const float*)d_in[2];
    const float* w_t      = (const float*)d_in[3];
    const float* att      = (const float*)d_in[4];
    const float* nbhd     = (const float*)d_in[5];
    const int*   rows     = (const int*)d_in[6];
    const int*   cols     = (const int*)d_in[7];

    float* out     = (float*)d_out;
    float* msg_src = out;                       // (N_SRC, 64)
    float* msg_tgt = out + (size_t)N_SRC * 64;  // (N_TGT, 64)

    // queues live in d_out (38.4 MB) as scratch; fully consumed by
    // scatter_queue before gather overwrites every output element.
    uint4* qT = (uint4*)d_out;                                   // 16,777,216 B
    uint4* qS = (uint4*)((char*)d_out + (size_t)QCAP * 8 * 16);  // 16,777,216 B

    char* ws = (char*)d_ws;
    // byte layout: total 56,801,032 B
    float*  s_msg  = (float*) (ws + 0);           // 25,600,000
    float*  t_msg  = (float*) (ws + 25600000);    // 12,800,000
    double* es_d   = (double*)(ws + 38400000);    //    800,000
    double* et_d   = (double*)(ws + 39200000);    //    400,000
    int*    cnt_r  = (int*)   (ws + 39600000);    //    200,000
    int*    cnt_c  = (int*)   (ws + 39800000);    //    400,000
    int*    qtails = (int*)   (ws + 40200000);    //      1,024 (16 ctrs x 64B)
    int*    ptr_r  = (int*)   (ws + 40201024);    //    200,004
    int*    ptr_c  = (int*)   (ws + 40401028);    //    400,004
    unsigned long long* srtT = (unsigned long long*)(ws + 40801032); // 8,000,000
    unsigned long long* srtS = (unsigned long long*)(ws + 48801032); // 8,000,000

    // zero cnt_r + cnt_c + qtails (contiguous)
    hipMemsetAsync(ws + 39600000, 0, 601024, stream);

    fused_histq_gemm<<<NHQ + GBLK, 256, 0, stream>>>(
        rows, cols, nbhd, cnt_r, cnt_c, qtails, qT, qS,
        x_source, x_target, w_s, w_t, att,
        s_msg, t_msg, es_d, et_d);

    scan_two<<<2, 1024, 0, stream>>>(cnt_r, cnt_c, ptr_r, ptr_c);

    scatter_queue<<<NSC, 256, 0, stream>>>(
        qT, qS, qtails, ptr_r, ptr_c, srtT, srtS);

    gather_both<<<(N_TGT + N_SRC + 3) / 4, 256, 0, stream>>>(
        (const int2*)srtT, ptr_r, s_msg, msg_tgt,
        (const int2*)srtS, ptr_c, t_msg, msg_src, es_d, et_d);
}